// Round 10
// baseline (130.023 us; speedup 1.0000x reference)
//
#include <hip/hip_runtime.h>
#include <hip/hip_bf16.h>
#include <math.h>

#define H 128
#define W 128
#define C 128
#define BATCH 2
#define NPIX (H*W)            // 16384
#define PX 32                 // pixels per dcn block
#define ZROW (2*NPIX)         // zero row index in xT (padding reads)

// ws layout (bytes): part 3538944 | wPack 294912 | wPack27 73728 | xT 8390656
#define WS_WPK_OFF   3538944
#define WS_WPK27_OFF 3833856
#define WS_XT_OFF    3907584   // total 12,298,240 B

typedef __attribute__((ext_vector_type(8))) short bf16x8;
typedef __attribute__((ext_vector_type(4))) float f32x4;

static __device__ __forceinline__ unsigned short f2bf(float f){
  unsigned u = __float_as_uint(f);
  u += 0x7FFF + ((u >> 16) & 1);          // RNE
  return (unsigned short)(u >> 16);
}

// ---------------------------------------------------------------------------
// Kernel 0: x (NCHW fp32) -> xT (NHWC bf16) + zero row at ZROW.
// ---------------------------------------------------------------------------
__global__ __launch_bounds__(256) void xpose_kernel(
    const float* __restrict__ x, unsigned short* __restrict__ xT)
{
  __shared__ float tile[128][65];
  int bidx = blockIdx.x;            // 512 = 2 b x 256 tiles
  int b  = bidx >> 8;
  int p0 = (bidx & 255) << 6;
  int t  = threadIdx.x;

  const float* xb = x + (long)b*C*NPIX;
#pragma unroll
  for (int q = 0; q < 8; ++q) {
    int idx  = q*256 + t;           // 2048 float4 units
    int c    = idx >> 4;
    int quad = idx & 15;
    float4 v = *(const float4*)(xb + (long)c*NPIX + p0 + quad*4);
    tile[c][quad*4+0] = v.x; tile[c][quad*4+1] = v.y;
    tile[c][quad*4+2] = v.z; tile[c][quad*4+3] = v.w;
  }
  __syncthreads();
#pragma unroll
  for (int r = 0; r < 4; ++r) {
    int u = r*256 + t;              // 1024 units: px = u>>4, seg(8ch) = u&15
    int px = u >> 4, seg = u & 15;
    unsigned pk[4];
#pragma unroll
    for (int e2 = 0; e2 < 4; ++e2) {
      float lo = tile[seg*8 + e2*2][px];
      float hi = tile[seg*8 + e2*2 + 1][px];
      pk[e2] = (unsigned)f2bf(lo) | ((unsigned)f2bf(hi) << 16);
    }
    *(uint4*)(xT + ((long)(b*NPIX + p0 + px))*C + seg*8) =
        make_uint4(pk[0],pk[1],pk[2],pk[3]);
  }
  if (bidx == 0 && t < 16)
    *(uint4*)(xT + (long)ZROW*C + t*8) = make_uint4(0,0,0,0);
}

// ---------------------------------------------------------------------------
// Kernel 1 (merged): pack w_conv -> wPack[kq][128][8] and [w_p;w_m;0] ->
// wPack27[kq][32][8], both bf16 under K-permutation k' = n*128 + c.
// Blocks 0..71 -> wPack, 72..89 -> wPack27.
// ---------------------------------------------------------------------------
__global__ __launch_bounds__(256) void wpack_all_kernel(
    const float* __restrict__ w_conv, const float* __restrict__ w_p,
    const float* __restrict__ w_m, unsigned short* __restrict__ wPack,
    unsigned short* __restrict__ wPack27)
{
  int blk = blockIdx.x;
  if (blk < 72) {
    int g  = blk*256 + threadIdx.x;         // 0..18431
    int oc = g & 127;
    int kq = g >> 7;                         // 0..143
    int n  = kq >> 4;
    int c0 = (kq & 15) * 8;
    const float* src = w_conv + oc*1152 + n;
    float f[8];
#pragma unroll
    for (int e = 0; e < 8; ++e) f[e] = src[(c0+e)*9];
    unsigned p0 = (unsigned)f2bf(f[0]) | ((unsigned)f2bf(f[1])<<16);
    unsigned p1 = (unsigned)f2bf(f[2]) | ((unsigned)f2bf(f[3])<<16);
    unsigned p2 = (unsigned)f2bf(f[4]) | ((unsigned)f2bf(f[5])<<16);
    unsigned p3 = (unsigned)f2bf(f[6]) | ((unsigned)f2bf(f[7])<<16);
    *(uint4*)(wPack + (long)g*8) = make_uint4(p0,p1,p2,p3);
  } else {
    int g = (blk-72)*256 + threadIdx.x;     // 0..4607
    int oc = g & 31;
    int kq = g >> 5;                         // 0..143
    int n  = kq >> 4;
    int c0 = (kq & 15) * 8;
    unsigned pk[4];
#pragma unroll
    for (int e2 = 0; e2 < 4; ++e2) {
      float f0 = 0.f, f1 = 0.f;
      int ca = c0 + e2*2, cb = ca + 1;
      if (oc < 18)      { f0 = w_p[(oc*C + ca)*9 + n];      f1 = w_p[(oc*C + cb)*9 + n]; }
      else if (oc < 27) { f0 = w_m[((oc-18)*C + ca)*9 + n]; f1 = w_m[((oc-18)*C + cb)*9 + n]; }
      pk[e2] = (unsigned)f2bf(f0) | ((unsigned)f2bf(f1)<<16);
    }
    *(uint4*)(wPack27 + (long)g*8) = make_uint4(pk[0],pk[1],pk[2],pk[3]);
  }
}

// ---------------------------------------------------------------------------
// Kernel 2: 27-channel offset/modulation conv as MFMA GEMM (unchanged R9).
// ---------------------------------------------------------------------------
__global__ __launch_bounds__(256) void off_kernel(
    const unsigned short* __restrict__ xT,
    const unsigned short* __restrict__ wPack27,
    float* __restrict__ part)
{
  __shared__ int mR[9*64];          // shifted row index per (n, px)
  int b     = blockIdx.x >> 8;      // grid 512 = 2 b x 256 tiles of 64 px
  int pbase = (blockIdx.x & 255) << 6;
  int tid = threadIdx.x, lane = tid & 63, wid = tid >> 6;

  for (int v = tid; v < 576; v += 256) {
    int px = v & 63, n = v >> 6;
    int p = pbase + px;
    int i = p >> 7, j = p & 127;
    int ii = i + n/3 - 1, jj = j + n%3 - 1;
    bool valid = ((unsigned)ii < 128u) && ((unsigned)jj < 128u);
    mR[v] = valid ? (b*NPIX + ii*W + jj) : ZROW;
  }
  __syncthreads();

  f32x4 acc[2];
  acc[0] = (f32x4){0.f,0.f,0.f,0.f};
  acc[1] = (f32x4){0.f,0.f,0.f,0.f};
  int col = lane & 15, kslot = lane >> 4;
  int mypx = wid*16 + col;

  bf16x8 aC[2][2], aN[2][2], bC[2], bN[2];

#define OLOADB(CC, DST) { int n_ = (CC) >> 1;                              \
  long row = mR[n_*64 + mypx];                                             \
  const unsigned short* bp = xT + row*C + ((CC)&1)*64 + kslot*8;           \
  DST[0] = *(const bf16x8*)bp; DST[1] = *(const bf16x8*)(bp + 32); }

#define OLOADA(CC, DST) { _Pragma("unroll")                                \
  for (int st = 0; st < 2; ++st) { _Pragma("unroll")                       \
    for (int o2 = 0; o2 < 2; ++o2) {                                       \
      int kq = (CC)*8 + st*4 + kslot;                                      \
      DST[st][o2] = *(const bf16x8*)(wPack27 + ((long)kq*32 + o2*16 + col)*8); } } }

#define OMF(BD, AD) { _Pragma("unroll")                                    \
  for (int st = 0; st < 2; ++st) {                                         \
    acc[0] = __builtin_amdgcn_mfma_f32_16x16x32_bf16(AD[st][0], BD[st], acc[0], 0,0,0); \
    acc[1] = __builtin_amdgcn_mfma_f32_16x16x32_bf16(AD[st][1], BD[st], acc[1], 0,0,0); } }

  OLOADB(0, bC) OLOADA(0, aC)
  for (int c2 = 0; c2 < 9; ++c2) {
    OLOADB(c2*2+1, bN) OLOADA(c2*2+1, aN)
    OMF(bC, aC)
    if (c2 < 8) { OLOADB(c2*2+2, bC) OLOADA(c2*2+2, aC) }
    OMF(bN, aN)
  }
#undef OLOADB
#undef OLOADA
#undef OMF

#pragma unroll
  for (int o2 = 0; o2 < 2; ++o2)
#pragma unroll
    for (int r = 0; r < 4; ++r) {
      int oc = o2*16 + kslot*4 + r;
      if (oc < 27)
        part[((long)b*27 + oc)*NPIX + pbase + mypx] = acc[o2][r];
    }
}

// ---------------------------------------------------------------------------
// Kernel 3: fused bilinear sampling + MFMA GEMM.
// NEW vs R9: full-n 2-deep gather prefetch. Per n (chunk pair 2n,2n+1) the
// 4 corner rows are loaded as 8x16B into a NAMED register set (rE/rO) one
// full n-iteration ahead (~400-600cy issue->use vs ~40cy in R9). 9 explicit
// bodies alternate sets (static indexing). Same bytes/transactions as R9.
// ---------------------------------------------------------------------------
__global__ __launch_bounds__(256) void dcn_kernel(
    const unsigned short* __restrict__ xT, const float* __restrict__ part,
    const float* __restrict__ b_p, const float* __restrict__ b_m,
    const unsigned short* __restrict__ wPack, float* __restrict__ out)
{
  __shared__ int4   mIv[9*PX];
  __shared__ float4 mWv[9*PX];
  __shared__ unsigned short sP[2][8*PX*8];

  int b     = blockIdx.x >> 9;
  int pbase = (blockIdx.x & 511) * PX;
  int tid   = threadIdx.x;
  int lane  = tid & 63;
  int wid   = tid >> 6;

  // ---- phase 0: sampling metadata ----
  for (int v = tid; v < 9*PX; v += 256) {
    int px = v & (PX-1);
    int n  = v >> 5;
    int p  = pbase + px;
    int i = p >> 7, j = p & 127;

    const float* pp = part + (long)b*27*NPIX + p;
    float offx = b_p[n]   + pp[(long)n*NPIX];
    float offy = b_p[9+n] + pp[(long)(9+n)*NPIX];
    float mm   = b_m[n]   + pp[(long)(18+n)*NPIX];
    float mv = 1.f/(1.f + expf(-mm));

    float px_ = offx + (float)(i+1) + (float)(n/3 - 1);
    float py_ = offy + (float)(j+1) + (float)(n%3 - 1);
    float fx = floorf(px_), fy = floorf(py_);
    int qltx = min(max((int)fx,     0), 129);
    int qlty = min(max((int)fy,     0), 129);
    int qrbx = min(max((int)fx + 1, 0), 129);
    int qrby = min(max((int)fy + 1, 0), 129);
    px_ = fminf(fmaxf(px_, 0.f), 129.f);
    py_ = fminf(fmaxf(py_, 0.f), 129.f);
    float gxl = 1.f + ((float)qltx - px_);
    float gxr = 1.f - ((float)qrbx - px_);
    float gyl = 1.f + ((float)qlty - py_);
    float gyr = 1.f - ((float)qrby - py_);

    int   qx[4] = {qltx, qrbx, qltx, qrbx};
    int   qy[4] = {qlty, qrby, qrby, qlty};
    float gw[4] = {gxl*gyl, gxr*gyr, gxl*gyr, gxr*gyl};
    int   ii[4]; float ww[4];
#pragma unroll
    for (int cn = 0; cn < 4; ++cn) {
      bool valid = (qx[cn]>=1)&&(qx[cn]<=H)&&(qy[cn]>=1)&&(qy[cn]<=W);
      ii[cn] = valid ? ((qx[cn]-1)*W + (qy[cn]-1)) : 0;
      ww[cn] = valid ? gw[cn]*mv : 0.f;
    }
    mIv[v] = make_int4(ii[0], ii[1], ii[2], ii[3]);
    mWv[v] = make_float4(ww[0], ww[1], ww[2], ww[3]);
  }
  __syncthreads();

  f32x4 acc[2][2];
#pragma unroll
  for (int a_ = 0; a_ < 2; ++a_)
#pragma unroll
    for (int b_ = 0; b_ < 2; ++b_) acc[a_][b_] = (f32x4){0.f,0.f,0.f,0.f};

  int spx   = tid >> 3;                // producer pixel (8 lanes/row)
  int ksl8  = tid & 7;                 // producer k-slot
  int col   = lane & 15;
  int kslot = lane >> 4;

  const unsigned short* xTb = xT + (long)b*NPIX*C;
  uint4 rE[8], rO[8];                  // [corner*2 + c-half], named sets
  bf16x8 aCur[2][2], aNxt[2][2];

#define ISSUE_ROWS(N, SET) {                                              \
  int4 iv = mIv[(N)*PX + spx];                                            \
  const unsigned short* q0 = xTb + (long)iv.x*C + ksl8*8;                 \
  const unsigned short* q1 = xTb + (long)iv.y*C + ksl8*8;                 \
  const unsigned short* q2 = xTb + (long)iv.z*C + ksl8*8;                 \
  const unsigned short* q3 = xTb + (long)iv.w*C + ksl8*8;                 \
  SET[0]=*(const uint4*)q0; SET[1]=*(const uint4*)(q0+64);                \
  SET[2]=*(const uint4*)q1; SET[3]=*(const uint4*)(q1+64);                \
  SET[4]=*(const uint4*)q2; SET[5]=*(const uint4*)(q2+64);                \
  SET[6]=*(const uint4*)q3; SET[7]=*(const uint4*)(q3+64); }

#define CLO(d) __uint_as_float((d)<<16)
#define CHI(d) __uint_as_float((d)&0xFFFF0000u)

#define COMPUTE_S(CC, BUF, SET) {                                         \
  int n_ = (CC) >> 1;                                                     \
  float4 wv = mWv[n_*PX + spx];                                           \
  unsigned pk[4];                                                         \
  _Pragma("unroll")                                                       \
  for (int jp = 0; jp < 4; ++jp) {                                        \
    unsigned d0 = ((const unsigned*)&SET[0 + ((CC)&1)])[jp];              \
    unsigned d1 = ((const unsigned*)&SET[2 + ((CC)&1)])[jp];              \
    unsigned d2 = ((const unsigned*)&SET[4 + ((CC)&1)])[jp];              \
    unsigned d3 = ((const unsigned*)&SET[6 + ((CC)&1)])[jp];              \
    float s0 = wv.x*CLO(d0) + wv.y*CLO(d1) + wv.z*CLO(d2) + wv.w*CLO(d3); \
    float s1 = wv.x*CHI(d0) + wv.y*CHI(d1) + wv.z*CHI(d2) + wv.w*CHI(d3); \
    pk[jp] = (unsigned)f2bf(s0) | ((unsigned)f2bf(s1)<<16);               \
  }                                                                       \
  *(uint4*)&sP[BUF][(ksl8*PX + spx)*8] = make_uint4(pk[0],pk[1],pk[2],pk[3]); }

#define ISSUE_A(CC, DST) { _Pragma("unroll")                              \
  for (int st = 0; st < 2; ++st) { _Pragma("unroll")                      \
    for (int o2 = 0; o2 < 2; ++o2) {                                      \
      int kq = (CC)*8 + st*4 + kslot;                                     \
      int oc = wid*32 + o2*16 + col;                                      \
      DST[st][o2] = *(const bf16x8*)(wPack + ((long)kq*128 + oc)*8);      \
    } } }

#define BARRIER {                                                         \
  __builtin_amdgcn_sched_barrier(0);                                      \
  asm volatile("s_waitcnt lgkmcnt(0)" ::: "memory");                      \
  __builtin_amdgcn_sched_barrier(0);                                      \
  __builtin_amdgcn_s_barrier();                                           \
  __builtin_amdgcn_sched_barrier(0); }

#define DO_MFMA(BUF, AFR) { _Pragma("unroll")                             \
  for (int st = 0; st < 2; ++st) {                                        \
    bf16x8 b0 = *(const bf16x8*)&sP[BUF][((st*4+kslot)*PX +      col)*8]; \
    bf16x8 b1 = *(const bf16x8*)&sP[BUF][((st*4+kslot)*PX + 16 + col)*8]; \
    acc[0][0] = __builtin_amdgcn_mfma_f32_16x16x32_bf16(AFR[st][0], b0, acc[0][0], 0,0,0); \
    acc[0][1] = __builtin_amdgcn_mfma_f32_16x16x32_bf16(AFR[st][0], b1, acc[0][1], 0,0,0); \
    acc[1][0] = __builtin_amdgcn_mfma_f32_16x16x32_bf16(AFR[st][1], b0, acc[1][0], 0,0,0); \
    acc[1][1] = __builtin_amdgcn_mfma_f32_16x16x32_bf16(AFR[st][1], b1, acc[1][1], 0,0,0); \
  } }

// One n-iteration: consume RC for chunks 2N/2N+1, prefetch RN for n=N+1.
// LDS hazards: buf0 write follows prev body's 2nd barrier (after its last
// buf0 read); buf1 write follows this body's 1st barrier. PREF is a literal
// 0/1 so the N=8 tail's OOB ISSUE_ROWS(9)/ISSUE_A(18) are dead-code removed.
#define NBODY(N, RC, RN, PREF) {                                          \
  COMPUTE_S(2*(N), 0, RC)                                                 \
  if (PREF) { ISSUE_ROWS((N)+1, RN) }                                     \
  BARRIER                                                                 \
  ISSUE_A(2*(N)+1, aNxt)                                                  \
  DO_MFMA(0, aCur)                                                        \
  COMPUTE_S(2*(N)+1, 1, RC)                                               \
  BARRIER                                                                 \
  if (PREF) { ISSUE_A(2*(N)+2, aCur) }                                    \
  DO_MFMA(1, aNxt)                                                        }

  ISSUE_ROWS(0, rE)
  ISSUE_A(0, aCur)

  NBODY(0, rE, rO, 1)
  NBODY(1, rO, rE, 1)
  NBODY(2, rE, rO, 1)
  NBODY(3, rO, rE, 1)
  NBODY(4, rE, rO, 1)
  NBODY(5, rO, rE, 1)
  NBODY(6, rE, rO, 1)
  NBODY(7, rO, rE, 1)
  NBODY(8, rE, rO, 0)

#undef ISSUE_ROWS
#undef CLO
#undef CHI
#undef COMPUTE_S
#undef ISSUE_A
#undef BARRIER
#undef DO_MFMA
#undef NBODY

  // ---- epilogue ----
  int row4 = (lane >> 4) * 4;
#pragma unroll
  for (int o2 = 0; o2 < 2; ++o2)
#pragma unroll
    for (int p2 = 0; p2 < 2; ++p2)
#pragma unroll
      for (int r = 0; r < 4; ++r) {
        int oc = wid*32 + o2*16 + row4 + r;
        int px = pbase + p2*16 + col;
        out[((long)(b*C + oc))*NPIX + px] = acc[o2][p2][r];
      }
}

// ---------------------------------------------------------------------------
extern "C" void kernel_launch(void* const* d_in, const int* in_sizes, int n_in,
                              void* d_out, int out_size, void* d_ws, size_t ws_size,
                              hipStream_t stream) {
  const float* x      = (const float*)d_in[0];
  const float* w_p    = (const float*)d_in[1];
  const float* b_p    = (const float*)d_in[2];
  const float* w_m    = (const float*)d_in[3];
  const float* b_m    = (const float*)d_in[4];
  const float* w_conv = (const float*)d_in[5];
  float* out = (float*)d_out;

  float*          part  = (float*)d_ws;
  unsigned short* wPk   = (unsigned short*)((char*)d_ws + WS_WPK_OFF);
  unsigned short* wPk27 = (unsigned short*)((char*)d_ws + WS_WPK27_OFF);
  unsigned short* xT    = (unsigned short*)((char*)d_ws + WS_XT_OFF);

  xpose_kernel   <<<512, 256, 0, stream>>>(x, xT);
  wpack_all_kernel<<<90, 256, 0, stream>>>(w_conv, w_p, w_m, wPk, wPk27);
  off_kernel     <<<512, 256, 0, stream>>>(xT, wPk27, part);
  dcn_kernel     <<<1024,256, 0, stream>>>(xT, part, b_p, b_m, wPk, out);
}

// Round 12
// 126.286 us; speedup vs baseline: 1.0296x; 1.0296x over previous
//
#include <hip/hip_runtime.h>
#include <hip/hip_bf16.h>
#include <math.h>

#define H 128
#define W 128
#define C 128
#define BATCH 2
#define NPIX (H*W)            // 16384
#define PX 32                 // pixels per dcn block
#define ZROW (2*NPIX)         // zero row index in xT (padding reads)

// ws layout (bytes): wPack 294912 | wPack27 73728 | xT 8390656  (no part!)
#define WS_WPK_OFF   0
#define WS_WPK27_OFF 294912
#define WS_XT_OFF    368640    // total 8,759,296 B

typedef __attribute__((ext_vector_type(8))) short bf16x8;
typedef __attribute__((ext_vector_type(4))) float f32x4;

static __device__ __forceinline__ unsigned short f2bf(float f){
  unsigned u = __float_as_uint(f);
  u += 0x7FFF + ((u >> 16) & 1);          // RNE
  return (unsigned short)(u >> 16);
}

// ---------------------------------------------------------------------------
// Kernel 0 (merged prep): blocks 0..511 transpose x -> xT bf16 (+zero row);
// blocks 512..583 pack w_conv -> wPack; blocks 584..601 pack w27 -> wPack27.
// K-permutation k' = n*128 + c throughout (proven R6-R10).
// ---------------------------------------------------------------------------
__global__ __launch_bounds__(256) void prep_kernel(
    const float* __restrict__ x, const float* __restrict__ w_conv,
    const float* __restrict__ w_p, const float* __restrict__ w_m,
    unsigned short* __restrict__ xT, unsigned short* __restrict__ wPack,
    unsigned short* __restrict__ wPack27)
{
  __shared__ float tile[128][65];
  int blk = blockIdx.x;
  int t   = threadIdx.x;

  if (blk < 512) {
    int b  = blk >> 8;
    int p0 = (blk & 255) << 6;
    const float* xb = x + (long)b*C*NPIX;
#pragma unroll
    for (int q = 0; q < 8; ++q) {
      int idx  = q*256 + t;
      int c    = idx >> 4;
      int quad = idx & 15;
      float4 v = *(const float4*)(xb + (long)c*NPIX + p0 + quad*4);
      tile[c][quad*4+0] = v.x; tile[c][quad*4+1] = v.y;
      tile[c][quad*4+2] = v.z; tile[c][quad*4+3] = v.w;
    }
    __syncthreads();
#pragma unroll
    for (int r = 0; r < 4; ++r) {
      int u = r*256 + t;
      int px = u >> 4, seg = u & 15;
      unsigned pk[4];
#pragma unroll
      for (int e2 = 0; e2 < 4; ++e2) {
        float lo = tile[seg*8 + e2*2][px];
        float hi = tile[seg*8 + e2*2 + 1][px];
        pk[e2] = (unsigned)f2bf(lo) | ((unsigned)f2bf(hi) << 16);
      }
      *(uint4*)(xT + ((long)(b*NPIX + p0 + px))*C + seg*8) =
          make_uint4(pk[0],pk[1],pk[2],pk[3]);
    }
    if (blk == 0 && t < 16)
      *(uint4*)(xT + (long)ZROW*C + t*8) = make_uint4(0,0,0,0);
  } else if (blk < 584) {
    int g  = (blk-512)*256 + t;             // 0..18431
    int oc = g & 127;
    int kq = g >> 7;
    int n  = kq >> 4;
    int c0 = (kq & 15) * 8;
    const float* src = w_conv + oc*1152 + n;
    float f[8];
#pragma unroll
    for (int e = 0; e < 8; ++e) f[e] = src[(c0+e)*9];
    unsigned p0 = (unsigned)f2bf(f[0]) | ((unsigned)f2bf(f[1])<<16);
    unsigned p1 = (unsigned)f2bf(f[2]) | ((unsigned)f2bf(f[3])<<16);
    unsigned p2 = (unsigned)f2bf(f[4]) | ((unsigned)f2bf(f[5])<<16);
    unsigned p3 = (unsigned)f2bf(f[6]) | ((unsigned)f2bf(f[7])<<16);
    *(uint4*)(wPack + (long)g*8) = make_uint4(p0,p1,p2,p3);
  } else {
    int g = (blk-584)*256 + t;              // 0..4607
    int oc = g & 31;
    int kq = g >> 5;
    int n  = kq >> 4;
    int c0 = (kq & 15) * 8;
    unsigned pk[4];
#pragma unroll
    for (int e2 = 0; e2 < 4; ++e2) {
      float f0 = 0.f, f1 = 0.f;
      int ca = c0 + e2*2, cb = ca + 1;
      if (oc < 18)      { f0 = w_p[(oc*C + ca)*9 + n];      f1 = w_p[(oc*C + cb)*9 + n]; }
      else if (oc < 27) { f0 = w_m[((oc-18)*C + ca)*9 + n]; f1 = w_m[((oc-18)*C + cb)*9 + n]; }
      pk[e2] = (unsigned)f2bf(f0) | ((unsigned)f2bf(f1)<<16);
    }
    *(uint4*)(wPack27 + (long)g*8) = make_uint4(pk[0],pk[1],pk[2],pk[3]);
  }
}

// ---------------------------------------------------------------------------
// Kernel 1: FULLY FUSED deformable conv.
// Prologue: 27-ch offset conv for this block's 32 px as a 32x32x1152 MFMA
// GEMM (wave = one 16x16 quadrant, K full; B-frags direct from xT at fixed
// shifted rows, zero row for borders) -> s27 LDS -> sampling metadata.
// Main loop: R9's proven 76-VGPR pipeline (gv4 gathers, 1 barrier/chunk).
// ---------------------------------------------------------------------------
__global__ __launch_bounds__(256) void dcn_kernel(
    const unsigned short* __restrict__ xT,
    const unsigned short* __restrict__ wPack27,
    const float* __restrict__ b_p, const float* __restrict__ b_m,
    const unsigned short* __restrict__ wPack, float* __restrict__ out)
{
  __shared__ int    mR[9*PX];                  // prologue shifted rows (abs)
  __shared__ float  s27[27][PX];               // prologue conv output
  __shared__ int4   mIv[9*PX];
  __shared__ float4 mWv[9*PX];
  __shared__ unsigned short sP[2][8*PX*8];

  int b     = blockIdx.x >> 9;
  int pbase = (blockIdx.x & 511) * PX;
  int tid   = threadIdx.x;
  int lane  = tid & 63;
  int wid   = tid >> 6;

  // ---- prologue A: shifted-row table ----
  for (int v = tid; v < 9*PX; v += 256) {
    int px = v & (PX-1), n = v >> 5;
    int p = pbase + px;
    int i = p >> 7, j = p & 127;
    int ii = i + n/3 - 1, jj = j + n%3 - 1;
    bool valid = ((unsigned)ii < 128u) && ((unsigned)jj < 128u);
    mR[v] = valid ? (b*NPIX + ii*W + jj) : ZROW;
  }
  __syncthreads();

  int col   = lane & 15;
  int kslot = lane >> 4;

  // ---- prologue B: 27-ch conv GEMM (wave quadrant: ochalf x pxhalf) ----
  {
    int ochalf = wid >> 1, pxhalf = wid & 1;
    int mycol  = pxhalf*16 + col;
    f32x4 a27 = (f32x4){0.f,0.f,0.f,0.f};
    bf16x8 pa0, pb0, pa1, pb1;

#define P27_LOAD(S, PA, PB) {                                              \
    int kq = (S)*4 + kslot;                                                \
    PA = *(const bf16x8*)(wPack27 + ((long)kq*32 + ochalf*16 + col)*8);    \
    long row = mR[((S)>>2)*PX + mycol];                                    \
    PB = *(const bf16x8*)(xT + row*C + (((S)&3)*32 + kslot*8)); }

    P27_LOAD(0, pa0, pb0)
#pragma unroll
    for (int s = 0; s < 36; s += 2) {
      if (s+1 < 36) { P27_LOAD(s+1, pa1, pb1) }
      a27 = __builtin_amdgcn_mfma_f32_16x16x32_bf16(pa0, pb0, a27, 0,0,0);
      if (s+2 < 36) { P27_LOAD(s+2, pa0, pb0) }
      if (s+1 < 36)
        a27 = __builtin_amdgcn_mfma_f32_16x16x32_bf16(pa1, pb1, a27, 0,0,0);
    }
#undef P27_LOAD
#pragma unroll
    for (int r = 0; r < 4; ++r) {
      int oc = ochalf*16 + kslot*4 + r;
      if (oc < 27) s27[oc][mycol] = a27[r];
    }
  }
  __syncthreads();

  // ---- prologue C: sampling metadata ----
  for (int v = tid; v < 9*PX; v += 256) {
    int px = v & (PX-1);
    int n  = v >> 5;
    int p  = pbase + px;
    int i = p >> 7, j = p & 127;

    float offx = b_p[n]   + s27[n][px];
    float offy = b_p[9+n] + s27[9+n][px];
    float mm   = b_m[n]   + s27[18+n][px];
    float mv = 1.f/(1.f + expf(-mm));

    float px_ = offx + (float)(i+1) + (float)(n/3 - 1);
    float py_ = offy + (float)(j+1) + (float)(n%3 - 1);
    float fx = floorf(px_), fy = floorf(py_);
    int qltx = min(max((int)fx,     0), 129);
    int qlty = min(max((int)fy,     0), 129);
    int qrbx = min(max((int)fx + 1, 0), 129);
    int qrby = min(max((int)fy + 1, 0), 129);
    px_ = fminf(fmaxf(px_, 0.f), 129.f);
    py_ = fminf(fmaxf(py_, 0.f), 129.f);
    float gxl = 1.f + ((float)qltx - px_);
    float gxr = 1.f - ((float)qrbx - px_);
    float gyl = 1.f + ((float)qlty - py_);
    float gyr = 1.f - ((float)qrby - py_);

    int   qx[4] = {qltx, qrbx, qltx, qrbx};
    int   qy[4] = {qlty, qrby, qrby, qlty};
    float gw[4] = {gxl*gyl, gxr*gyr, gxl*gyr, gxr*gyl};
    int   ii[4]; float ww[4];
#pragma unroll
    for (int cn = 0; cn < 4; ++cn) {
      bool valid = (qx[cn]>=1)&&(qx[cn]<=H)&&(qy[cn]>=1)&&(qy[cn]<=W);
      ii[cn] = valid ? ((qx[cn]-1)*W + (qy[cn]-1)) : 0;
      ww[cn] = valid ? gw[cn]*mv : 0.f;
    }
    mIv[v] = make_int4(ii[0], ii[1], ii[2], ii[3]);
    mWv[v] = make_float4(ww[0], ww[1], ww[2], ww[3]);
  }
  __syncthreads();

  // ---- main loop (R9 pipeline, 76-VGPR gather scheme) ----
  f32x4 acc[2][2];
#pragma unroll
  for (int a_ = 0; a_ < 2; ++a_)
#pragma unroll
    for (int b_ = 0; b_ < 2; ++b_) acc[a_][b_] = (f32x4){0.f,0.f,0.f,0.f};

  int spx   = tid >> 3;                // producer pixel (8 lanes/row)
  int ksl8  = tid & 7;                 // producer k-slot

  const unsigned short* xTb = xT + (long)b*NPIX*C;
  uint4 gv4[4];
  bf16x8 aCur[2][2], aNxt[2][2];

#define ISSUE_G(CC) {                                                     \
  int n_ = (CC) >> 1;                                                     \
  int4 iv = mIv[n_*PX + spx];                                             \
  int coff = ((CC)&1)*64 + ksl8*8;                                        \
  gv4[0] = *(const uint4*)(xTb + (long)iv.x*C + coff);                    \
  gv4[1] = *(const uint4*)(xTb + (long)iv.y*C + coff);                    \
  gv4[2] = *(const uint4*)(xTb + (long)iv.z*C + coff);                    \
  gv4[3] = *(const uint4*)(xTb + (long)iv.w*C + coff); }

#define GCD(cn, j) (((const unsigned*)&gv4[cn])[(j)])
#define CLO(d) __uint_as_float((d)<<16)
#define CHI(d) __uint_as_float((d)&0xFFFF0000u)

#define COMPUTE_S(CC, BUF) {                                              \
  int n_ = (CC) >> 1;                                                     \
  float4 wv = mWv[n_*PX + spx];                                           \
  unsigned pk[4];                                                         \
  _Pragma("unroll")                                                       \
  for (int jp = 0; jp < 4; ++jp) {                                        \
    unsigned d0=GCD(0,jp), d1=GCD(1,jp), d2=GCD(2,jp), d3=GCD(3,jp);      \
    float s0 = wv.x*CLO(d0) + wv.y*CLO(d1) + wv.z*CLO(d2) + wv.w*CLO(d3); \
    float s1 = wv.x*CHI(d0) + wv.y*CHI(d1) + wv.z*CHI(d2) + wv.w*CHI(d3); \
    pk[jp] = (unsigned)f2bf(s0) | ((unsigned)f2bf(s1)<<16);               \
  }                                                                       \
  *(uint4*)&sP[BUF][(ksl8*PX + spx)*8] = make_uint4(pk[0],pk[1],pk[2],pk[3]); }

#define ISSUE_A(CC, DST) { _Pragma("unroll")                              \
  for (int st = 0; st < 2; ++st) { _Pragma("unroll")                      \
    for (int o2 = 0; o2 < 2; ++o2) {                                      \
      int kq = (CC)*8 + st*4 + kslot;                                     \
      int oc = wid*32 + o2*16 + col;                                      \
      DST[st][o2] = *(const bf16x8*)(wPack + ((long)kq*128 + oc)*8);      \
    } } }

#define BARRIER {                                                         \
  __builtin_amdgcn_sched_barrier(0);                                      \
  asm volatile("s_waitcnt lgkmcnt(0)" ::: "memory");                      \
  __builtin_amdgcn_sched_barrier(0);                                      \
  __builtin_amdgcn_s_barrier();                                           \
  __builtin_amdgcn_sched_barrier(0); }

#define DO_MFMA(BUF, AFR) { _Pragma("unroll")                             \
  for (int st = 0; st < 2; ++st) {                                        \
    bf16x8 b0 = *(const bf16x8*)&sP[BUF][((st*4+kslot)*PX +      col)*8]; \
    bf16x8 b1 = *(const bf16x8*)&sP[BUF][((st*4+kslot)*PX + 16 + col)*8]; \
    acc[0][0] = __builtin_amdgcn_mfma_f32_16x16x32_bf16(AFR[st][0], b0, acc[0][0], 0,0,0); \
    acc[0][1] = __builtin_amdgcn_mfma_f32_16x16x32_bf16(AFR[st][0], b1, acc[0][1], 0,0,0); \
    acc[1][0] = __builtin_amdgcn_mfma_f32_16x16x32_bf16(AFR[st][1], b0, acc[1][0], 0,0,0); \
    acc[1][1] = __builtin_amdgcn_mfma_f32_16x16x32_bf16(AFR[st][1], b1, acc[1][1], 0,0,0); \
  } }

  ISSUE_G(0)
  ISSUE_A(0, aCur)

  for (int cc2 = 0; cc2 < 9; ++cc2) {
    int ccE = cc2*2, ccO = cc2*2 + 1;

    COMPUTE_S(ccE, 0)                  // consumes gv4(ccE)
    ISSUE_G(ccO)                       // in flight across barrier
    BARRIER
    ISSUE_A(ccO, aNxt)
    DO_MFMA(0, aCur)

    COMPUTE_S(ccO, 1)
    if (cc2 < 8) { ISSUE_G(ccE+2) }
    BARRIER
    if (cc2 < 8) { ISSUE_A(ccE+2, aCur) }
    DO_MFMA(1, aNxt)
  }
#undef ISSUE_G
#undef GCD
#undef CLO
#undef CHI
#undef COMPUTE_S
#undef ISSUE_A
#undef BARRIER
#undef DO_MFMA

  // ---- epilogue ----
  int row4 = (lane >> 4) * 4;
#pragma unroll
  for (int o2 = 0; o2 < 2; ++o2)
#pragma unroll
    for (int p2 = 0; p2 < 2; ++p2)
#pragma unroll
      for (int r = 0; r < 4; ++r) {
        int oc = wid*32 + o2*16 + row4 + r;
        int px = pbase + p2*16 + col;
        out[((long)(b*C + oc))*NPIX + px] = acc[o2][p2][r];
      }
}

// ---------------------------------------------------------------------------
extern "C" void kernel_launch(void* const* d_in, const int* in_sizes, int n_in,
                              void* d_out, int out_size, void* d_ws, size_t ws_size,
                              hipStream_t stream) {
  const float* x      = (const float*)d_in[0];
  const float* w_p    = (const float*)d_in[1];
  const float* b_p    = (const float*)d_in[2];
  const float* w_m    = (const float*)d_in[3];
  const float* b_m    = (const float*)d_in[4];
  const float* w_conv = (const float*)d_in[5];
  float* out = (float*)d_out;

  unsigned short* wPk   = (unsigned short*)((char*)d_ws + WS_WPK_OFF);
  unsigned short* wPk27 = (unsigned short*)((char*)d_ws + WS_WPK27_OFF);
  unsigned short* xT    = (unsigned short*)((char*)d_ws + WS_XT_OFF);

  prep_kernel<<<602, 256, 0, stream>>>(x, w_conv, w_p, w_m, xT, wPk, wPk27);
  dcn_kernel <<<1024,256, 0, stream>>>(xT, wPk27, b_p, b_m, wPk, out);
}